// Round 1
// baseline (705.801 us; speedup 1.0000x reference)
//
#include <hip/hip_runtime.h>

constexpr int kB = 256;
constexpr int kNC = 99;
constexpr int kN = 100;
constexpr int kC = 128;
constexpr int kH = 512;
constexpr int kL = 3;
constexpr int kNT = kB * kN;   // 25600
constexpr float kEps = 1e-5f;

// per-channel BN affine from raw (sum, sumsq) stats; stats==nullptr -> identity
__device__ __forceinline__ void affine_from_stats(
    const float* __restrict__ stats, const float* __restrict__ gamma,
    const float* __restrict__ beta, int c, float& sc, float& sh) {
  if (stats != nullptr) {
    float s = stats[c], sq = stats[kC + c];
    float m = s * (1.0f / kNT);
    float v = sq * (1.0f / kNT) - m * m;
    float rs = rsqrtf(v + kEps);
    sc = gamma[c] * rs;
    sh = beta[c] - m * sc;
  } else {
    sc = 1.0f;
    sh = 0.0f;
  }
}

// initial embeddings -> out [NT, C]
__global__ __launch_bounds__(256) void k_init(
    const float* __restrict__ dxy, const float* __restrict__ cxy,
    const float* __restrict__ dem, const float* __restrict__ Wd,
    const float* __restrict__ bd, const float* __restrict__ Wi,
    const float* __restrict__ bi, float* __restrict__ out) {
  int idx = blockIdx.x * 256 + threadIdx.x;      // < NT*C exactly
  int row = idx >> 7, c = idx & 127;
  int b = row / kN, j = row - b * kN;
  float v;
  if (j == 0) {
    v = dxy[b * 2] * Wd[c] + dxy[b * 2 + 1] * Wd[kC + c] + bd[c];
  } else {
    int q = b * kNC + (j - 1);
    v = cxy[q * 2] * Wi[c] + cxy[q * 2 + 1] * Wi[kC + c] +
        dem[q] * Wi[2 * kC + c] + bi[c];
  }
  out[idx] = v;
}

// h = affine(yin) @ W   (M=NT, K=C=128, N=C=128), 64-row tiles
__global__ __launch_bounds__(256) void k_gemm(
    const float* __restrict__ yin, const float* __restrict__ stats,
    const float* __restrict__ gamma, const float* __restrict__ beta,
    const float* __restrict__ W, float* __restrict__ hout) {
  __shared__ float s_scale[kC], s_shift[kC];
  __shared__ float xs[64][kC + 4];
  __shared__ float wc[64][kC];
  const int tid = threadIdx.x;
  if (tid < kC) affine_from_stats(stats, gamma, beta, tid, s_scale[tid], s_shift[tid]);
  __syncthreads();
  const int rb = blockIdx.x * 64;
#pragma unroll
  for (int i = 0; i < 8; ++i) {
    int li = i * 1024 + tid * 4;
    int lr = li >> 7, lc = li & 127;
    float4 g = *(const float4*)(yin + (size_t)(rb + lr) * kC + lc);
    xs[lr][lc + 0] = fmaf(g.x, s_scale[lc + 0], s_shift[lc + 0]);
    xs[lr][lc + 1] = fmaf(g.y, s_scale[lc + 1], s_shift[lc + 1]);
    xs[lr][lc + 2] = fmaf(g.z, s_scale[lc + 2], s_shift[lc + 2]);
    xs[lr][lc + 3] = fmaf(g.w, s_scale[lc + 3], s_shift[lc + 3]);
  }
  const int ct = tid & 15, rt = tid >> 4;
  const int r0 = rt * 4, cA = ct * 4, cB = 64 + ct * 4;
  float acc[4][8];
#pragma unroll
  for (int i = 0; i < 4; ++i)
#pragma unroll
    for (int j = 0; j < 8; ++j) acc[i][j] = 0.0f;

  for (int k0 = 0; k0 < kC; k0 += 64) {
    __syncthreads();
#pragma unroll
    for (int i = 0; i < 8; ++i) {
      int li = i * 1024 + tid * 4;
      int kr = li >> 7, kc = li & 127;
      *(float4*)&wc[kr][kc] = *(const float4*)(W + (size_t)(k0 + kr) * kC + kc);
    }
    __syncthreads();
#pragma unroll 4
    for (int k = 0; k < 64; ++k) {
      float av[4];
#pragma unroll
      for (int i = 0; i < 4; ++i) av[i] = xs[r0 + i][k0 + k];
      float4 wA = *(const float4*)&wc[k][cA];
      float4 wB = *(const float4*)&wc[k][cB];
#pragma unroll
      for (int i = 0; i < 4; ++i) {
        acc[i][0] = fmaf(av[i], wA.x, acc[i][0]);
        acc[i][1] = fmaf(av[i], wA.y, acc[i][1]);
        acc[i][2] = fmaf(av[i], wA.z, acc[i][2]);
        acc[i][3] = fmaf(av[i], wA.w, acc[i][3]);
        acc[i][4] = fmaf(av[i], wB.x, acc[i][4]);
        acc[i][5] = fmaf(av[i], wB.y, acc[i][5]);
        acc[i][6] = fmaf(av[i], wB.z, acc[i][6]);
        acc[i][7] = fmaf(av[i], wB.w, acc[i][7]);
      }
    }
  }
#pragma unroll
  for (int i = 0; i < 4; ++i) {
    float4 oA = make_float4(acc[i][0], acc[i][1], acc[i][2], acc[i][3]);
    float4 oB = make_float4(acc[i][4], acc[i][5], acc[i][6], acc[i][7]);
    *(float4*)(hout + (size_t)(rb + r0 + i) * kC + cA) = oA;
    *(float4*)(hout + (size_t)(rb + r0 + i) * kC + cB) = oB;
  }
}

// per-graph prefix aggregation: yA = affine(yprev) + rsqrt-prefix(h) + gb, + BN stats
__global__ __launch_bounds__(128) void k_agg(
    const float* __restrict__ yprev, const float* __restrict__ h,
    const float* __restrict__ stats_prev, const float* __restrict__ gamma_p,
    const float* __restrict__ beta_p, const float* __restrict__ gb,
    float* __restrict__ stats_out, float* __restrict__ yA) {
  const int b = blockIdx.x, c = threadIdx.x;
  float sc, sh;
  affine_from_stats(stats_prev, gamma_p, beta_p, c, sc, sh);
  const float gbc = gb[c];
  float s = 0.0f, lsum = 0.0f, lsq = 0.0f;
  size_t base = (size_t)b * kN * kC + c;
#pragma unroll 4
  for (int j = 0; j < kN; ++j) {
    float r = rsqrtf((float)(j + 1));
    s = fmaf(h[base + (size_t)j * kC], r, s);
    float xv = fmaf(yprev[base + (size_t)j * kC], sc, sh);
    float yv = xv + fmaf(s, r, gbc);
    yA[base + (size_t)j * kC] = yv;
    lsum += yv;
    lsq = fmaf(yv, yv, lsq);
  }
  atomicAdd(&stats_out[c], lsum);
  atomicAdd(&stats_out[kC + c], lsq);
}

// fused FF: x = affine(yA); yB = x + relu(x@W1+b1)@W2 + b2 ; + BN stats
__global__ __launch_bounds__(256) void k_ff(
    const float* __restrict__ yA, const float* __restrict__ stats_in,
    const float* __restrict__ gamma, const float* __restrict__ beta,
    const float* __restrict__ W1, const float* __restrict__ b1,
    const float* __restrict__ W2, const float* __restrict__ b2,
    float* __restrict__ stats_out, float* __restrict__ yB) {
  __shared__ float s_scale[kC], s_shift[kC];
  __shared__ float xs[32][kC + 4];     // 16.9 KB (row stride 528B, 16B aligned)
  __shared__ float wb[32 * kH];        // 64 KB: W1 k-chunks, then hid[32][512]
  __shared__ float w2b[64 * kC];       // 32 KB: W2 k-chunks
  __shared__ float s_sum[kC], s_sq[kC];
  const int tid = threadIdx.x;
  if (tid < kC) {
    affine_from_stats(stats_in, gamma, beta, tid, s_scale[tid], s_shift[tid]);
    s_sum[tid] = 0.0f;
    s_sq[tid] = 0.0f;
  }
  __syncthreads();
  const int rb = blockIdx.x * 32;
#pragma unroll
  for (int i = 0; i < 4; ++i) {
    int li = i * 1024 + tid * 4;
    int lr = li >> 7, lc = li & 127;
    float4 g = *(const float4*)(yA + (size_t)(rb + lr) * kC + lc);
    xs[lr][lc + 0] = fmaf(g.x, s_scale[lc + 0], s_shift[lc + 0]);
    xs[lr][lc + 1] = fmaf(g.y, s_scale[lc + 1], s_shift[lc + 1]);
    xs[lr][lc + 2] = fmaf(g.z, s_scale[lc + 2], s_shift[lc + 2]);
    xs[lr][lc + 3] = fmaf(g.w, s_scale[lc + 3], s_shift[lc + 3]);
  }
  const int ct = tid & 31, rt = tid >> 5;
  const int r0 = rt * 4, ct4 = ct * 4;

  // phase 1: hid[32][512] = relu(xs @ W1 + b1)
  float hacc[4][4][4];
#pragma unroll
  for (int i = 0; i < 4; ++i)
#pragma unroll
    for (int q = 0; q < 4; ++q)
#pragma unroll
      for (int j = 0; j < 4; ++j) hacc[i][q][j] = 0.0f;

  for (int k0 = 0; k0 < kC; k0 += 32) {
    __syncthreads();
#pragma unroll
    for (int i = 0; i < 16; ++i) {
      int li = i * 1024 + tid * 4;
      int kr = li >> 9, kc = li & 511;
      *(float4*)&wb[kr * kH + kc] = *(const float4*)(W1 + (size_t)(k0 + kr) * kH + kc);
    }
    __syncthreads();
#pragma unroll 2
    for (int k = 0; k < 32; ++k) {
      float av[4];
#pragma unroll
      for (int i = 0; i < 4; ++i) av[i] = xs[r0 + i][k0 + k];
#pragma unroll
      for (int q = 0; q < 4; ++q) {
        float4 w = *(const float4*)&wb[k * kH + q * kC + ct4];
#pragma unroll
        for (int i = 0; i < 4; ++i) {
          hacc[i][q][0] = fmaf(av[i], w.x, hacc[i][q][0]);
          hacc[i][q][1] = fmaf(av[i], w.y, hacc[i][q][1]);
          hacc[i][q][2] = fmaf(av[i], w.z, hacc[i][q][2]);
          hacc[i][q][3] = fmaf(av[i], w.w, hacc[i][q][3]);
        }
      }
    }
  }
  __syncthreads();   // all W1 reads done; reuse wb for hid
#pragma unroll
  for (int q = 0; q < 4; ++q) {
    float4 bb = *(const float4*)(b1 + q * kC + ct4);
#pragma unroll
    for (int i = 0; i < 4; ++i) {
      float4 hv;
      hv.x = fmaxf(hacc[i][q][0] + bb.x, 0.0f);
      hv.y = fmaxf(hacc[i][q][1] + bb.y, 0.0f);
      hv.z = fmaxf(hacc[i][q][2] + bb.z, 0.0f);
      hv.w = fmaxf(hacc[i][q][3] + bb.w, 0.0f);
      *(float4*)&wb[(r0 + i) * kH + q * kC + ct4] = hv;
    }
  }
  __syncthreads();

  // phase 2: out[32][128] = xs + hid @ W2 + b2
  float oacc[4][4];
#pragma unroll
  for (int i = 0; i < 4; ++i)
#pragma unroll
    for (int j = 0; j < 4; ++j) oacc[i][j] = 0.0f;

  for (int kk0 = 0; kk0 < kH; kk0 += 64) {
    __syncthreads();
#pragma unroll
    for (int i = 0; i < 8; ++i) {
      int li = i * 1024 + tid * 4;
      int kr = li >> 7, kc = li & 127;
      *(float4*)&w2b[kr * kC + kc] = *(const float4*)(W2 + (size_t)(kk0 + kr) * kC + kc);
    }
    __syncthreads();
#pragma unroll 4
    for (int k = 0; k < 64; ++k) {
      float4 w = *(const float4*)&w2b[k * kC + ct4];
      float av[4];
#pragma unroll
      for (int i = 0; i < 4; ++i) av[i] = wb[(r0 + i) * kH + kk0 + k];
#pragma unroll
      for (int i = 0; i < 4; ++i) {
        oacc[i][0] = fmaf(av[i], w.x, oacc[i][0]);
        oacc[i][1] = fmaf(av[i], w.y, oacc[i][1]);
        oacc[i][2] = fmaf(av[i], w.z, oacc[i][2]);
        oacc[i][3] = fmaf(av[i], w.w, oacc[i][3]);
      }
    }
  }

  // epilogue: bias + residual, store, BN stats
  float4 bb2 = *(const float4*)(b2 + ct4);
  float psum[4] = {0, 0, 0, 0}, psq[4] = {0, 0, 0, 0};
#pragma unroll
  for (int i = 0; i < 4; ++i) {
    int r = r0 + i;
    float4 xr = *(const float4*)&xs[r][ct4];
    float4 o;
    o.x = oacc[i][0] + bb2.x + xr.x;
    o.y = oacc[i][1] + bb2.y + xr.y;
    o.z = oacc[i][2] + bb2.z + xr.z;
    o.w = oacc[i][3] + bb2.w + xr.w;
    *(float4*)(yB + (size_t)(rb + r) * kC + ct4) = o;
    psum[0] += o.x; psq[0] = fmaf(o.x, o.x, psq[0]);
    psum[1] += o.y; psq[1] = fmaf(o.y, o.y, psq[1]);
    psum[2] += o.z; psq[2] = fmaf(o.z, o.z, psq[2]);
    psum[3] += o.w; psq[3] = fmaf(o.w, o.w, psq[3]);
  }
#pragma unroll
  for (int j = 0; j < 4; ++j) {
    atomicAdd(&s_sum[ct4 + j], psum[j]);
    atomicAdd(&s_sq[ct4 + j], psq[j]);
  }
  __syncthreads();
  if (tid < kC) {
    atomicAdd(&stats_out[tid], s_sum[tid]);
    atomicAdd(&stats_out[kC + tid], s_sq[tid]);
  }
}

// final BN apply + nodes out + per-graph mean
__global__ __launch_bounds__(128) void k_out(
    const float* __restrict__ yB, const float* __restrict__ stats,
    const float* __restrict__ gamma, const float* __restrict__ beta,
    float* __restrict__ out) {
  const int b = blockIdx.x, c = threadIdx.x;
  float sc, sh;
  affine_from_stats(stats, gamma, beta, c, sc, sh);
  float acc = 0.0f;
  size_t base = (size_t)b * kN * kC + c;
#pragma unroll 4
  for (int j = 0; j < kN; ++j) {
    float xv = fmaf(yB[base + (size_t)j * kC], sc, sh);
    out[base + (size_t)j * kC] = xv;
    acc += xv;
  }
  out[(size_t)kNT * kC + (size_t)b * kC + c] = acc * (1.0f / kN);
}

extern "C" void kernel_launch(void* const* d_in, const int* in_sizes, int n_in,
                              void* d_out, int out_size, void* d_ws, size_t ws_size,
                              hipStream_t stream) {
  const float* depot_xy    = (const float*)d_in[0];
  const float* customer_xy = (const float*)d_in[1];
  const float* demand      = (const float*)d_in[2];
  const float* W_depot     = (const float*)d_in[3];
  const float* b_depot     = (const float*)d_in[4];
  const float* W_init      = (const float*)d_in[5];
  const float* b_init      = (const float*)d_in[6];
  const float* gcn_W       = (const float*)d_in[7];
  const float* gcn_b       = (const float*)d_in[8];
  const float* bn_gamma    = (const float*)d_in[9];
  const float* bn_beta     = (const float*)d_in[10];
  const float* ff_W1       = (const float*)d_in[11];
  const float* ff_b1       = (const float*)d_in[12];
  const float* ff_W2       = (const float*)d_in[13];
  const float* ff_b2       = (const float*)d_in[14];

  float* ws    = (float*)d_ws;
  float* yA    = ws;
  float* yB    = ws + (size_t)kNT * kC;
  float* hbuf  = ws + 2 * (size_t)kNT * kC;
  float* stats = ws + 3 * (size_t)kNT * kC;   // 6 slots x (sum[128], sumsq[128])

  hipMemsetAsync(stats, 0, kL * 2 * 2 * kC * sizeof(float), stream);
  k_init<<<kNT * kC / 256, 256, 0, stream>>>(depot_xy, customer_xy, demand,
                                             W_depot, b_depot, W_init, b_init, yB);
  for (int l = 0; l < kL; ++l) {
    const float* sp = (l == 0) ? nullptr : stats + ((l - 1) * 2 + 1) * 2 * kC;
    const float* gp = (l == 0) ? nullptr : bn_gamma + (l - 1) * kC;
    const float* bp = (l == 0) ? nullptr : bn_beta + (l - 1) * kC;
    float* s0 = stats + (l * 2 + 0) * 2 * kC;
    float* s1 = stats + (l * 2 + 1) * 2 * kC;
    k_gemm<<<kNT / 64, 256, 0, stream>>>(yB, sp, gp, bp, gcn_W + (size_t)l * kC * kC, hbuf);
    k_agg<<<kB, 128, 0, stream>>>(yB, hbuf, sp, gp, bp, gcn_b + l * kC, s0, yA);
    k_ff<<<kNT / 32, 256, 0, stream>>>(yA, s0, bn_gamma + l * kC, bn_beta + l * kC,
                                       ff_W1 + (size_t)l * kC * kH, ff_b1 + l * kH,
                                       ff_W2 + (size_t)l * kH * kC, ff_b2 + l * kC,
                                       s1, yB);
  }
  k_out<<<kB, 128, 0, stream>>>(yB, stats + (2 * 2 + 1) * 2 * kC,
                                bn_gamma + 2 * kC, bn_beta + 2 * kC, (float*)d_out);
}

// Round 2
// 311.949 us; speedup vs baseline: 2.2626x; 2.2626x over previous
//
#include <hip/hip_runtime.h>

constexpr int kB = 256;
constexpr int kNC = 99;
constexpr int kN = 100;
constexpr int kC = 128;
constexpr int kH = 512;
constexpr int kL = 3;
constexpr int kNT = kB * kN;   // 25600
constexpr float kEps = 1e-5f;

typedef unsigned short u16;
typedef unsigned int u32;
typedef __attribute__((ext_vector_type(8))) __bf16 bf16x8;
typedef __attribute__((ext_vector_type(4))) float f32x4;

__device__ __forceinline__ u16 f2bf(float x) {
  union { float f; u32 u; } v; v.f = x;
  u32 r = (v.u + 0x7FFFu + ((v.u >> 16) & 1u)) >> 16;
  return (u16)r;
}
__device__ __forceinline__ float bf2f(u16 h) {
  union { u32 u; float f; } v; v.u = ((u32)h) << 16;
  return v.f;
}

// per-channel BN affine from raw (sum, sumsq) stats; stats==nullptr -> identity
__device__ __forceinline__ void affine_from_stats(
    const float* __restrict__ stats, const float* __restrict__ gamma,
    const float* __restrict__ beta, int c, float& sc, float& sh) {
  if (stats != nullptr) {
    float s = stats[c], sq = stats[kC + c];
    float m = s * (1.0f / kNT);
    float v = sq * (1.0f / kNT) - m * m;
    float rs = rsqrtf(v + kEps);
    sc = gamma[c] * rs;
    sh = beta[c] - m * sc;
  } else {
    sc = 1.0f;
    sh = 0.0f;
  }
}

// ---- pack all GEMM weights (gcn_W, ff_W1, ff_W2) into bf16 MFMA B-fragment
// layout. frag f = n_blk*nK + k_blk; within frag: lane l, elem j (0..7):
//   B[k_blk*32 + (l>>4)*8 + j][n_blk*16 + (l&15)]
// stored at dst[f*512 + l*8 + j]. Per layer: gcn 32 frags, W1 128, W2 128.
__global__ __launch_bounds__(256) void k_pack(
    const float* __restrict__ gcnW, const float* __restrict__ W1,
    const float* __restrict__ W2, u16* __restrict__ dst) {
  int wid = blockIdx.x * 4 + (threadIdx.x >> 6);
  int lane = threadIdx.x & 63;
  if (wid >= kL * 288) return;
  int layer = wid / 288, r = wid % 288;
  const float* src; int N, nK, fi;
  if (r < 32)       { src = gcnW + layer * kC * kC; N = kC; nK = 4;  fi = r; }
  else if (r < 160) { src = W1   + layer * kC * kH; N = kH; nK = 4;  fi = r - 32; }
  else              { src = W2   + layer * kH * kC; N = kC; nK = 16; fi = r - 160; }
  int nb = fi / nK, kb = fi % nK;
  int col  = nb * 16 + (lane & 15);
  int krow = kb * 32 + (lane >> 4) * 8;
  u16* out = dst + ((size_t)(layer * 288 + r)) * 512 + lane * 8;
  ushort4 lo, hi;
  lo.x = f2bf(src[(size_t)(krow + 0) * N + col]);
  lo.y = f2bf(src[(size_t)(krow + 1) * N + col]);
  lo.z = f2bf(src[(size_t)(krow + 2) * N + col]);
  lo.w = f2bf(src[(size_t)(krow + 3) * N + col]);
  hi.x = f2bf(src[(size_t)(krow + 4) * N + col]);
  hi.y = f2bf(src[(size_t)(krow + 5) * N + col]);
  hi.z = f2bf(src[(size_t)(krow + 6) * N + col]);
  hi.w = f2bf(src[(size_t)(krow + 7) * N + col]);
  *(ushort4*)out = lo;
  *(ushort4*)(out + 4) = hi;
}

// initial embeddings -> out [NT, C]
__global__ __launch_bounds__(256) void k_init(
    const float* __restrict__ dxy, const float* __restrict__ cxy,
    const float* __restrict__ dem, const float* __restrict__ Wd,
    const float* __restrict__ bd, const float* __restrict__ Wi,
    const float* __restrict__ bi, float* __restrict__ out) {
  int idx = blockIdx.x * 256 + threadIdx.x;      // < NT*C exactly
  int row = idx >> 7, c = idx & 127;
  int b = row / kN, j = row - b * kN;
  float v;
  if (j == 0) {
    v = dxy[b * 2] * Wd[c] + dxy[b * 2 + 1] * Wd[kC + c] + bd[c];
  } else {
    int q = b * kNC + (j - 1);
    v = cxy[q * 2] * Wi[c] + cxy[q * 2 + 1] * Wi[kC + c] +
        dem[q] * Wi[2 * kC + c] + bi[c];
  }
  out[idx] = v;
}

// h = affine(yin) @ W  (MFMA bf16). 64-row tile, 4 waves (one per 16 rows).
__global__ __launch_bounds__(256) void k_gemm(
    const float* __restrict__ yin, const float* __restrict__ stats,
    const float* __restrict__ gamma, const float* __restrict__ beta,
    const u16* __restrict__ Wp, float* __restrict__ hout) {
  __shared__ float s_scale[kC], s_shift[kC];
  __shared__ u16 xs[64][136];
  const int tid = threadIdx.x;
  if (tid < kC) affine_from_stats(stats, gamma, beta, tid, s_scale[tid], s_shift[tid]);
  __syncthreads();
  const int rb = blockIdx.x * 64;
#pragma unroll
  for (int i = 0; i < 8; ++i) {
    int li = i * 1024 + tid * 4;
    int lr = li >> 7, lc = li & 127;
    float4 g = *(const float4*)(yin + (size_t)(rb + lr) * kC + lc);
    ushort4 h4;
    h4.x = f2bf(fmaf(g.x, s_scale[lc + 0], s_shift[lc + 0]));
    h4.y = f2bf(fmaf(g.y, s_scale[lc + 1], s_shift[lc + 1]));
    h4.z = f2bf(fmaf(g.z, s_scale[lc + 2], s_shift[lc + 2]));
    h4.w = f2bf(fmaf(g.w, s_scale[lc + 3], s_shift[lc + 3]));
    *(ushort4*)&xs[lr][lc] = h4;
  }
  __syncthreads();
  const int wave = tid >> 6, lane = tid & 63;
  const int row0 = wave * 16;
  const int arow = row0 + (lane & 15);
  const int kofs = (lane >> 4) * 8;
  bf16x8 a[4];
#pragma unroll
  for (int kb = 0; kb < 4; ++kb)
    a[kb] = *(const bf16x8*)&xs[arow][kb * 32 + kofs];
  const int crow = row0 + (lane >> 4) * 4;
  const int ccol = lane & 15;
  const u16* wf = Wp + lane * 8;
#pragma unroll
  for (int nb = 0; nb < 8; nb += 2) {
    f32x4 acc0 = {0.f, 0.f, 0.f, 0.f}, acc1 = {0.f, 0.f, 0.f, 0.f};
#pragma unroll
    for (int kb = 0; kb < 4; ++kb) {
      bf16x8 b0 = *(const bf16x8*)(wf + (size_t)((nb + 0) * 4 + kb) * 512);
      bf16x8 b1 = *(const bf16x8*)(wf + (size_t)((nb + 1) * 4 + kb) * 512);
      acc0 = __builtin_amdgcn_mfma_f32_16x16x32_bf16(a[kb], b0, acc0, 0, 0, 0);
      acc1 = __builtin_amdgcn_mfma_f32_16x16x32_bf16(a[kb], b1, acc1, 0, 0, 0);
    }
#pragma unroll
    for (int r = 0; r < 4; ++r) {
      hout[(size_t)(rb + crow + r) * kC + (nb + 0) * 16 + ccol] = acc0[r];
      hout[(size_t)(rb + crow + r) * kC + (nb + 1) * 16 + ccol] = acc1[r];
    }
  }
}

// per-graph prefix aggregation: yA = affine(yprev) + rsqrt-prefix(h) + gb, + BN stats
__global__ __launch_bounds__(128) void k_agg(
    const float* __restrict__ yprev, const float* __restrict__ h,
    const float* __restrict__ stats_prev, const float* __restrict__ gamma_p,
    const float* __restrict__ beta_p, const float* __restrict__ gb,
    float* __restrict__ stats_out, float* __restrict__ yA) {
  const int b = blockIdx.x, c = threadIdx.x;
  float sc, sh;
  affine_from_stats(stats_prev, gamma_p, beta_p, c, sc, sh);
  const float gbc = gb[c];
  float s = 0.0f, lsum = 0.0f, lsq = 0.0f;
  size_t base = (size_t)b * kN * kC + c;
#pragma unroll 4
  for (int j = 0; j < kN; ++j) {
    float r = rsqrtf((float)(j + 1));
    s = fmaf(h[base + (size_t)j * kC], r, s);
    float xv = fmaf(yprev[base + (size_t)j * kC], sc, sh);
    float yv = xv + fmaf(s, r, gbc);
    yA[base + (size_t)j * kC] = yv;
    lsum += yv;
    lsq = fmaf(yv, yv, lsq);
  }
  atomicAdd(&stats_out[c], lsum);
  atomicAdd(&stats_out[kC + c], lsq);
}

// fused FF (MFMA bf16): x = affine(yA); yB = x + relu(x@W1+b1)@W2 + b2 ; + BN stats
// 32-row tile, 2 waves (16 rows each). hid kept in LDS as bf16.
__global__ __launch_bounds__(128) void k_ff(
    const float* __restrict__ yA, const float* __restrict__ stats_in,
    const float* __restrict__ gamma, const float* __restrict__ beta,
    const u16* __restrict__ W1p, const float* __restrict__ b1,
    const u16* __restrict__ W2p, const float* __restrict__ b2,
    float* __restrict__ stats_out, float* __restrict__ yB) {
  __shared__ float s_scale[kC], s_shift[kC], s_sum[kC], s_sq[kC];
  __shared__ float s_b1[kH];
  __shared__ u16 xs[32][136];
  __shared__ u16 hid[32][520];
  const int tid = threadIdx.x;
  if (tid < kC) {
    affine_from_stats(stats_in, gamma, beta, tid, s_scale[tid], s_shift[tid]);
    s_sum[tid] = 0.0f;
    s_sq[tid] = 0.0f;
  }
  *(float4*)&s_b1[tid * 4] = *(const float4*)(b1 + tid * 4);
  __syncthreads();
  const int rb = blockIdx.x * 32;
#pragma unroll
  for (int i = 0; i < 8; ++i) {
    int li = i * 512 + tid * 4;
    int lr = li >> 7, lc = li & 127;
    float4 g = *(const float4*)(yA + (size_t)(rb + lr) * kC + lc);
    ushort4 h4;
    h4.x = f2bf(fmaf(g.x, s_scale[lc + 0], s_shift[lc + 0]));
    h4.y = f2bf(fmaf(g.y, s_scale[lc + 1], s_shift[lc + 1]));
    h4.z = f2bf(fmaf(g.z, s_scale[lc + 2], s_shift[lc + 2]));
    h4.w = f2bf(fmaf(g.w, s_scale[lc + 3], s_shift[lc + 3]));
    *(ushort4*)&xs[lr][lc] = h4;
  }
  __syncthreads();
  const int wave = tid >> 6, lane = tid & 63;
  const int row0 = wave * 16;
  const int arow = row0 + (lane & 15);
  const int kofs = (lane >> 4) * 8;
  const int crow = row0 + (lane >> 4) * 4;
  const int ccol = lane & 15;

  // ---- phase 1: hid = relu(xs @ W1 + b1), bf16 into LDS
  bf16x8 a[4];
#pragma unroll
  for (int kb = 0; kb < 4; ++kb)
    a[kb] = *(const bf16x8*)&xs[arow][kb * 32 + kofs];
  const u16* w1f = W1p + lane * 8;
#pragma unroll 4
  for (int nb = 0; nb < 32; nb += 2) {
    f32x4 acc0 = {0.f, 0.f, 0.f, 0.f}, acc1 = {0.f, 0.f, 0.f, 0.f};
#pragma unroll
    for (int kb = 0; kb < 4; ++kb) {
      bf16x8 b0 = *(const bf16x8*)(w1f + (size_t)((nb + 0) * 4 + kb) * 512);
      bf16x8 b1v = *(const bf16x8*)(w1f + (size_t)((nb + 1) * 4 + kb) * 512);
      acc0 = __builtin_amdgcn_mfma_f32_16x16x32_bf16(a[kb], b0, acc0, 0, 0, 0);
      acc1 = __builtin_amdgcn_mfma_f32_16x16x32_bf16(a[kb], b1v, acc1, 0, 0, 0);
    }
    int c0 = (nb + 0) * 16 + ccol, c1 = (nb + 1) * 16 + ccol;
    float bb0 = s_b1[c0], bb1 = s_b1[c1];
#pragma unroll
    for (int r = 0; r < 4; ++r) {
      hid[crow + r][c0] = f2bf(fmaxf(acc0[r] + bb0, 0.0f));
      hid[crow + r][c1] = f2bf(fmaxf(acc1[r] + bb1, 0.0f));
    }
  }
  __syncthreads();

  // ---- phase 2: out = xs + hid @ W2 + b2
  f32x4 oacc[8];
#pragma unroll
  for (int nb = 0; nb < 8; ++nb) oacc[nb] = {0.f, 0.f, 0.f, 0.f};
  const u16* w2f = W2p + lane * 8;
  for (int kb = 0; kb < 16; ++kb) {
    bf16x8 ha = *(const bf16x8*)&hid[arow][kb * 32 + kofs];
#pragma unroll
    for (int nb = 0; nb < 8; ++nb) {
      bf16x8 b = *(const bf16x8*)(w2f + (size_t)(nb * 16 + kb) * 512);
      oacc[nb] = __builtin_amdgcn_mfma_f32_16x16x32_bf16(ha, b, oacc[nb], 0, 0, 0);
    }
  }

  // ---- epilogue: bias + residual, store, BN stats
#pragma unroll
  for (int nb = 0; nb < 8; ++nb) {
    int c = nb * 16 + ccol;
    float bb = b2[c];
    float s = 0.0f, q = 0.0f;
#pragma unroll
    for (int r = 0; r < 4; ++r) {
      float xv = bf2f(xs[crow + r][c]);
      float o = oacc[nb][r] + bb + xv;
      yB[(size_t)(rb + crow + r) * kC + c] = o;
      s += o;
      q = fmaf(o, o, q);
    }
    atomicAdd(&s_sum[c], s);
    atomicAdd(&s_sq[c], q);
  }
  __syncthreads();
  if (tid < kC) {
    atomicAdd(&stats_out[tid], s_sum[tid]);
    atomicAdd(&stats_out[kC + tid], s_sq[tid]);
  }
}

// final BN apply + nodes out + per-graph mean
__global__ __launch_bounds__(128) void k_out(
    const float* __restrict__ yB, const float* __restrict__ stats,
    const float* __restrict__ gamma, const float* __restrict__ beta,
    float* __restrict__ out) {
  const int b = blockIdx.x, c = threadIdx.x;
  float sc, sh;
  affine_from_stats(stats, gamma, beta, c, sc, sh);
  float acc = 0.0f;
  size_t base = (size_t)b * kN * kC + c;
#pragma unroll 4
  for (int j = 0; j < kN; ++j) {
    float xv = fmaf(yB[base + (size_t)j * kC], sc, sh);
    out[base + (size_t)j * kC] = xv;
    acc += xv;
  }
  out[(size_t)kNT * kC + (size_t)b * kC + c] = acc * (1.0f / kN);
}

extern "C" void kernel_launch(void* const* d_in, const int* in_sizes, int n_in,
                              void* d_out, int out_size, void* d_ws, size_t ws_size,
                              hipStream_t stream) {
  const float* depot_xy    = (const float*)d_in[0];
  const float* customer_xy = (const float*)d_in[1];
  const float* demand      = (const float*)d_in[2];
  const float* W_depot     = (const float*)d_in[3];
  const float* b_depot     = (const float*)d_in[4];
  const float* W_init      = (const float*)d_in[5];
  const float* b_init      = (const float*)d_in[6];
  const float* gcn_W       = (const float*)d_in[7];
  const float* gcn_b       = (const float*)d_in[8];
  const float* bn_gamma    = (const float*)d_in[9];
  const float* bn_beta     = (const float*)d_in[10];
  const float* ff_W1       = (const float*)d_in[11];
  const float* ff_b1       = (const float*)d_in[12];
  const float* ff_W2       = (const float*)d_in[13];
  const float* ff_b2       = (const float*)d_in[14];

  float* ws    = (float*)d_ws;
  float* yA    = ws;
  float* yB    = ws + (size_t)kNT * kC;
  float* hbuf  = ws + 2 * (size_t)kNT * kC;
  float* stats = ws + 3 * (size_t)kNT * kC;   // 6 slots x (sum[128], sumsq[128])
  u16*   wpack = (u16*)(stats + kL * 2 * 2 * kC);

  hipMemsetAsync(stats, 0, kL * 2 * 2 * kC * sizeof(float), stream);
  k_pack<<<(kL * 288 + 3) / 4, 256, 0, stream>>>(gcn_W, ff_W1, ff_W2, wpack);
  k_init<<<kNT * kC / 256, 256, 0, stream>>>(depot_xy, customer_xy, demand,
                                             W_depot, b_depot, W_init, b_init, yB);
  for (int l = 0; l < kL; ++l) {
    const float* sp = (l == 0) ? nullptr : stats + ((l - 1) * 2 + 1) * 2 * kC;
    const float* gp = (l == 0) ? nullptr : bn_gamma + (l - 1) * kC;
    const float* bp = (l == 0) ? nullptr : bn_beta + (l - 1) * kC;
    float* s0 = stats + (l * 2 + 0) * 2 * kC;
    float* s1 = stats + (l * 2 + 1) * 2 * kC;
    const u16* wg  = wpack + (size_t)(l * 288 + 0) * 512;
    const u16* w1p = wpack + (size_t)(l * 288 + 32) * 512;
    const u16* w2p = wpack + (size_t)(l * 288 + 160) * 512;
    k_gemm<<<kNT / 64, 256, 0, stream>>>(yB, sp, gp, bp, wg, hbuf);
    k_agg<<<kB, 128, 0, stream>>>(yB, hbuf, sp, gp, bp, gcn_b + l * kC, s0, yA);
    k_ff<<<kNT / 32, 128, 0, stream>>>(yA, s0, bn_gamma + l * kC, bn_beta + l * kC,
                                       w1p, ff_b1 + l * kH,
                                       w2p, ff_b2 + l * kC,
                                       s1, yB);
  }
  k_out<<<kB, 128, 0, stream>>>(yB, stats + (2 * 2 + 1) * 2 * kC,
                                bn_gamma + 2 * kC, bn_beta + 2 * kC, (float*)d_out);
}

// Round 3
// 190.217 us; speedup vs baseline: 3.7105x; 1.6400x over previous
//
#include <hip/hip_runtime.h>

constexpr int kB = 256;
constexpr int kNC = 99;
constexpr int kN = 100;
constexpr int kC = 128;
constexpr int kH = 512;
constexpr int kL = 3;
constexpr int kNT = kB * kN;   // 25600
constexpr float kEps = 1e-5f;

typedef unsigned short u16;
typedef unsigned int u32;
typedef __attribute__((ext_vector_type(8))) __bf16 bf16x8;
typedef __attribute__((ext_vector_type(4))) float f32x4;

__device__ __forceinline__ u16 f2bf(float x) {
  union { float f; u32 u; } v; v.f = x;
  u32 r = (v.u + 0x7FFFu + ((v.u >> 16) & 1u)) >> 16;
  return (u16)r;
}

// per-channel BN affine from raw (sum, sumsq) stats; stats==nullptr -> identity
__device__ __forceinline__ void affine_from_stats(
    const float* __restrict__ stats, const float* __restrict__ gamma,
    const float* __restrict__ beta, int c, float& sc, float& sh) {
  if (stats != nullptr) {
    float s = stats[c], sq = stats[kC + c];
    float m = s * (1.0f / kNT);
    float v = sq * (1.0f / kNT) - m * m;
    float rs = rsqrtf(v + kEps);
    sc = gamma[c] * rs;
    sh = beta[c] - m * sc;
  } else {
    sc = 1.0f;
    sh = 0.0f;
  }
}

// ---- pack all GEMM weights into bf16 MFMA B-fragment layout.
// frag f = nb*nK + kb; lane l, elem j: B[kb*32 + (l>>4)*8 + j][nb*16 + (l&15)]
__global__ __launch_bounds__(256) void k_pack(
    const float* __restrict__ gcnW, const float* __restrict__ W1,
    const float* __restrict__ W2, u16* __restrict__ dst) {
  int wid = blockIdx.x * 4 + (threadIdx.x >> 6);
  int lane = threadIdx.x & 63;
  if (wid >= kL * 288) return;
  int layer = wid / 288, r = wid % 288;
  const float* src; int N, nK, fi;
  if (r < 32)       { src = gcnW + layer * kC * kC; N = kC; nK = 4;  fi = r; }
  else if (r < 160) { src = W1   + layer * kC * kH; N = kH; nK = 4;  fi = r - 32; }
  else              { src = W2   + layer * kH * kC; N = kC; nK = 16; fi = r - 160; }
  int nb = fi / nK, kb = fi % nK;
  int col  = nb * 16 + (lane & 15);
  int krow = kb * 32 + (lane >> 4) * 8;
  u16* out = dst + ((size_t)(layer * 288 + r)) * 512 + lane * 8;
  ushort4 lo, hi;
  lo.x = f2bf(src[(size_t)(krow + 0) * N + col]);
  lo.y = f2bf(src[(size_t)(krow + 1) * N + col]);
  lo.z = f2bf(src[(size_t)(krow + 2) * N + col]);
  lo.w = f2bf(src[(size_t)(krow + 3) * N + col]);
  hi.x = f2bf(src[(size_t)(krow + 4) * N + col]);
  hi.y = f2bf(src[(size_t)(krow + 5) * N + col]);
  hi.z = f2bf(src[(size_t)(krow + 6) * N + col]);
  hi.w = f2bf(src[(size_t)(krow + 7) * N + col]);
  *(ushort4*)out = lo;
  *(ushort4*)(out + 4) = hi;
}

// initial embeddings -> out [NT, C]
__global__ __launch_bounds__(256) void k_init(
    const float* __restrict__ dxy, const float* __restrict__ cxy,
    const float* __restrict__ dem, const float* __restrict__ Wd,
    const float* __restrict__ bd, const float* __restrict__ Wi,
    const float* __restrict__ bi, float* __restrict__ out) {
  int idx = blockIdx.x * 256 + threadIdx.x;
  int row = idx >> 7, c = idx & 127;
  int b = row / kN, j = row - b * kN;
  float v;
  if (j == 0) {
    v = dxy[b * 2] * Wd[c] + dxy[b * 2 + 1] * Wd[kC + c] + bd[c];
  } else {
    int q = b * kNC + (j - 1);
    v = cxy[q * 2] * Wi[c] + cxy[q * 2 + 1] * Wi[kC + c] +
        dem[q] * Wi[2 * kC + c] + bi[c];
  }
  out[idx] = v;
}

// h = affine(yin) @ W  (MFMA bf16). 32-row tile, 4 waves; wave w -> cols [w*32, w*32+32)
__global__ __launch_bounds__(256) void k_gemm(
    const float* __restrict__ yin, const float* __restrict__ stats,
    const float* __restrict__ gamma, const float* __restrict__ beta,
    const u16* __restrict__ Wp, float* __restrict__ hout) {
  __shared__ float s_scale[kC], s_shift[kC];
  __shared__ u16 xs[32][136];
  const int tid = threadIdx.x;
  if (tid < kC) affine_from_stats(stats, gamma, beta, tid, s_scale[tid], s_shift[tid]);
  __syncthreads();
  const int rb = blockIdx.x * 32;
#pragma unroll
  for (int i = 0; i < 4; ++i) {
    int li = i * 1024 + tid * 4;
    int lr = li >> 7, lc = li & 127;
    float4 g = *(const float4*)(yin + (size_t)(rb + lr) * kC + lc);
    ushort4 h4;
    h4.x = f2bf(fmaf(g.x, s_scale[lc + 0], s_shift[lc + 0]));
    h4.y = f2bf(fmaf(g.y, s_scale[lc + 1], s_shift[lc + 1]));
    h4.z = f2bf(fmaf(g.z, s_scale[lc + 2], s_shift[lc + 2]));
    h4.w = f2bf(fmaf(g.w, s_scale[lc + 3], s_shift[lc + 3]));
    *(ushort4*)&xs[lr][lc] = h4;
  }
  __syncthreads();
  const int wave = tid >> 6, lane = tid & 63;
  const int arow = lane & 15, kofs = (lane >> 4) * 8;
  const int crow = (lane >> 4) * 4, ccol = lane & 15;
  bf16x8 a[2][4];
#pragma unroll
  for (int rb2 = 0; rb2 < 2; ++rb2)
#pragma unroll
    for (int kb = 0; kb < 4; ++kb)
      a[rb2][kb] = *(const bf16x8*)&xs[rb2 * 16 + arow][kb * 32 + kofs];
  const u16* wf = Wp + lane * 8;
  f32x4 acc[2][2];
#pragma unroll
  for (int i = 0; i < 2; ++i)
#pragma unroll
    for (int j = 0; j < 2; ++j) acc[i][j] = {0.f, 0.f, 0.f, 0.f};
#pragma unroll
  for (int kb = 0; kb < 4; ++kb) {
    bf16x8 b0 = *(const bf16x8*)(wf + (size_t)((wave * 2 + 0) * 4 + kb) * 512);
    bf16x8 b1 = *(const bf16x8*)(wf + (size_t)((wave * 2 + 1) * 4 + kb) * 512);
    acc[0][0] = __builtin_amdgcn_mfma_f32_16x16x32_bf16(a[0][kb], b0, acc[0][0], 0, 0, 0);
    acc[0][1] = __builtin_amdgcn_mfma_f32_16x16x32_bf16(a[0][kb], b1, acc[0][1], 0, 0, 0);
    acc[1][0] = __builtin_amdgcn_mfma_f32_16x16x32_bf16(a[1][kb], b0, acc[1][0], 0, 0, 0);
    acc[1][1] = __builtin_amdgcn_mfma_f32_16x16x32_bf16(a[1][kb], b1, acc[1][1], 0, 0, 0);
  }
#pragma unroll
  for (int rb2 = 0; rb2 < 2; ++rb2)
#pragma unroll
    for (int nb2 = 0; nb2 < 2; ++nb2)
#pragma unroll
      for (int r = 0; r < 4; ++r)
        hout[(size_t)(rb + rb2 * 16 + crow + r) * kC + (wave * 2 + nb2) * 16 + ccol] =
            acc[rb2][nb2][r];
}

// per-graph prefix aggregation, 4-way j-split parallel prefix
__global__ __launch_bounds__(512) void k_agg(
    const float* __restrict__ yprev, const float* __restrict__ h,
    const float* __restrict__ stats_prev, const float* __restrict__ gamma_p,
    const float* __restrict__ beta_p, const float* __restrict__ gb,
    float* __restrict__ stats_out, float* __restrict__ yA) {
  __shared__ float sP[4][kC];
  __shared__ float s_sum[kC], s_sq[kC];
  const int b = blockIdx.x;
  const int c = threadIdx.x & 127, jh = threadIdx.x >> 7;
  float sc, sh;
  affine_from_stats(stats_prev, gamma_p, beta_p, c, sc, sh);
  if (jh == 0) { s_sum[c] = 0.0f; s_sq[c] = 0.0f; }
  const float gbc = gb[c];
  const size_t base = (size_t)b * kN * kC + c;
  const int j0 = jh * 25;
  float p = 0.0f;
#pragma unroll
  for (int jj = 0; jj < 25; ++jj)
    p = fmaf(h[base + (size_t)(j0 + jj) * kC], rsqrtf((float)(j0 + jj + 1)), p);
  sP[jh][c] = p;
  __syncthreads();
  float s = 0.0f;
  for (int q = 0; q < jh; ++q) s += sP[q][c];
  float lsum = 0.0f, lsq = 0.0f;
#pragma unroll
  for (int jj = 0; jj < 25; ++jj) {
    int j = j0 + jj;
    float r = rsqrtf((float)(j + 1));
    s = fmaf(h[base + (size_t)j * kC], r, s);
    float xv = fmaf(yprev[base + (size_t)j * kC], sc, sh);
    float yv = xv + fmaf(s, r, gbc);
    yA[base + (size_t)j * kC] = yv;
    lsum += yv;
    lsq = fmaf(yv, yv, lsq);
  }
  atomicAdd(&s_sum[c], lsum);
  atomicAdd(&s_sq[c], lsq);
  __syncthreads();
  if (jh == 0) {
    atomicAdd(&stats_out[c], s_sum[c]);
    atomicAdd(&stats_out[kC + c], s_sq[c]);
  }
}

// fused FF (MFMA bf16): 32-row tile, 8 waves. phase1 N-split (64 cols/wave),
// phase2 N-split (16 cols/wave). hid transposed via LDS.
__global__ __launch_bounds__(512) void k_ff(
    const float* __restrict__ yA, const float* __restrict__ stats_in,
    const float* __restrict__ gamma, const float* __restrict__ beta,
    const u16* __restrict__ W1p, const float* __restrict__ b1,
    const u16* __restrict__ W2p, const float* __restrict__ b2,
    float* __restrict__ stats_out, float* __restrict__ yB) {
  __shared__ float s_scale[kC], s_shift[kC], s_sum[kC], s_sq[kC];
  __shared__ float s_b1[kH];
  __shared__ u16 xs[32][136];
  __shared__ u16 hid[32][520];
  const int tid = threadIdx.x;
  if (tid < kC) {
    affine_from_stats(stats_in, gamma, beta, tid, s_scale[tid], s_shift[tid]);
    s_sum[tid] = 0.0f;
    s_sq[tid] = 0.0f;
  }
  if (tid < 128) ((float4*)s_b1)[tid] = ((const float4*)b1)[tid];
  __syncthreads();
  const int rb = blockIdx.x * 32;
#pragma unroll
  for (int i = 0; i < 2; ++i) {
    int li = i * 2048 + tid * 4;
    int lr = li >> 7, lc = li & 127;
    float4 g = *(const float4*)(yA + (size_t)(rb + lr) * kC + lc);
    ushort4 h4;
    h4.x = f2bf(fmaf(g.x, s_scale[lc + 0], s_shift[lc + 0]));
    h4.y = f2bf(fmaf(g.y, s_scale[lc + 1], s_shift[lc + 1]));
    h4.z = f2bf(fmaf(g.z, s_scale[lc + 2], s_shift[lc + 2]));
    h4.w = f2bf(fmaf(g.w, s_scale[lc + 3], s_shift[lc + 3]));
    *(ushort4*)&xs[lr][lc] = h4;
  }
  __syncthreads();
  const int wave = tid >> 6, lane = tid & 63;
  const int arow = lane & 15, kofs = (lane >> 4) * 8;
  const int crow = (lane >> 4) * 4, ccol = lane & 15;
  bf16x8 a[2][4];
#pragma unroll
  for (int rb2 = 0; rb2 < 2; ++rb2)
#pragma unroll
    for (int kb = 0; kb < 4; ++kb)
      a[rb2][kb] = *(const bf16x8*)&xs[rb2 * 16 + arow][kb * 32 + kofs];

  // ---- phase 1: hid = relu(xs @ W1 + b1); wave handles nb = wave*4 .. wave*4+3
  const u16* w1f = W1p + lane * 8;
#pragma unroll
  for (int t = 0; t < 4; ++t) {
    const int nb = wave * 4 + t;
    f32x4 acc0 = {0.f, 0.f, 0.f, 0.f}, acc1 = {0.f, 0.f, 0.f, 0.f};
#pragma unroll
    for (int kb = 0; kb < 4; ++kb) {
      bf16x8 bfrag = *(const bf16x8*)(w1f + (size_t)(nb * 4 + kb) * 512);
      acc0 = __builtin_amdgcn_mfma_f32_16x16x32_bf16(a[0][kb], bfrag, acc0, 0, 0, 0);
      acc1 = __builtin_amdgcn_mfma_f32_16x16x32_bf16(a[1][kb], bfrag, acc1, 0, 0, 0);
    }
    const int c = nb * 16 + ccol;
    const float bbias = s_b1[c];
#pragma unroll
    for (int r = 0; r < 4; ++r) {
      hid[crow + r][c]      = f2bf(fmaxf(acc0[r] + bbias, 0.0f));
      hid[16 + crow + r][c] = f2bf(fmaxf(acc1[r] + bbias, 0.0f));
    }
  }
  __syncthreads();

  // ---- phase 2: out = x + hid @ W2 + b2; wave handles nb = wave
  const u16* w2f = W2p + lane * 8;
  f32x4 oacc0 = {0.f, 0.f, 0.f, 0.f}, oacc1 = {0.f, 0.f, 0.f, 0.f};
#pragma unroll
  for (int kb = 0; kb < 16; ++kb) {
    bf16x8 ha0 = *(const bf16x8*)&hid[arow][kb * 32 + kofs];
    bf16x8 ha1 = *(const bf16x8*)&hid[16 + arow][kb * 32 + kofs];
    bf16x8 bfrag = *(const bf16x8*)(w2f + (size_t)(wave * 16 + kb) * 512);
    oacc0 = __builtin_amdgcn_mfma_f32_16x16x32_bf16(ha0, bfrag, oacc0, 0, 0, 0);
    oacc1 = __builtin_amdgcn_mfma_f32_16x16x32_bf16(ha1, bfrag, oacc1, 0, 0, 0);
  }

  // ---- epilogue: bias + f32 residual, store, BN stats
  const int c = wave * 16 + ccol;
  const float sc = s_scale[c], sh = s_shift[c], bb = b2[c];
  float psum = 0.0f, psq = 0.0f;
#pragma unroll
  for (int rb2 = 0; rb2 < 2; ++rb2) {
#pragma unroll
    for (int r = 0; r < 4; ++r) {
      int row = rb + rb2 * 16 + crow + r;
      float xv = fmaf(yA[(size_t)row * kC + c], sc, sh);
      float o = (rb2 ? oacc1[r] : oacc0[r]) + bb + xv;
      yB[(size_t)row * kC + c] = o;
      psum += o;
      psq = fmaf(o, o, psq);
    }
  }
  atomicAdd(&s_sum[c], psum);
  atomicAdd(&s_sq[c], psq);
  __syncthreads();
  if (tid < kC) {
    atomicAdd(&stats_out[tid], s_sum[tid]);
    atomicAdd(&stats_out[kC + tid], s_sq[tid]);
  }
}

// final BN apply + nodes out + per-graph mean, 4-way j-split
__global__ __launch_bounds__(512) void k_out(
    const float* __restrict__ yB, const float* __restrict__ stats,
    const float* __restrict__ gamma, const float* __restrict__ beta,
    float* __restrict__ out) {
  __shared__ float sP[4][kC];
  const int b = blockIdx.x;
  const int c = threadIdx.x & 127, jh = threadIdx.x >> 7;
  float sc, sh;
  affine_from_stats(stats, gamma, beta, c, sc, sh);
  float acc = 0.0f;
  const size_t base = (size_t)b * kN * kC + c;
  const int j0 = jh * 25;
#pragma unroll
  for (int jj = 0; jj < 25; ++jj) {
    float xv = fmaf(yB[base + (size_t)(j0 + jj) * kC], sc, sh);
    out[base + (size_t)(j0 + jj) * kC] = xv;
    acc += xv;
  }
  sP[jh][c] = acc;
  __syncthreads();
  if (jh == 0)
    out[(size_t)kNT * kC + (size_t)b * kC + c] =
        (sP[0][c] + sP[1][c] + sP[2][c] + sP[3][c]) * (1.0f / kN);
}

extern "C" void kernel_launch(void* const* d_in, const int* in_sizes, int n_in,
                              void* d_out, int out_size, void* d_ws, size_t ws_size,
                              hipStream_t stream) {
  const float* depot_xy    = (const float*)d_in[0];
  const float* customer_xy = (const float*)d_in[1];
  const float* demand      = (const float*)d_in[2];
  const float* W_depot     = (const float*)d_in[3];
  const float* b_depot     = (const float*)d_in[4];
  const float* W_init      = (const float*)d_in[5];
  const float* b_init      = (const float*)d_in[6];
  const float* gcn_W       = (const float*)d_in[7];
  const float* gcn_b       = (const float*)d_in[8];
  const float* bn_gamma    = (const float*)d_in[9];
  const float* bn_beta     = (const float*)d_in[10];
  const float* ff_W1       = (const float*)d_in[11];
  const float* ff_b1       = (const float*)d_in[12];
  const float* ff_W2       = (const float*)d_in[13];
  const float* ff_b2       = (const float*)d_in[14];

  float* ws    = (float*)d_ws;
  float* yA    = ws;
  float* yB    = ws + (size_t)kNT * kC;
  float* hbuf  = ws + 2 * (size_t)kNT * kC;
  float* stats = ws + 3 * (size_t)kNT * kC;   // 6 slots x (sum[128], sumsq[128])
  u16*   wpack = (u16*)(stats + kL * 2 * 2 * kC);

  hipMemsetAsync(stats, 0, kL * 2 * 2 * kC * sizeof(float), stream);
  k_pack<<<(kL * 288 + 3) / 4, 256, 0, stream>>>(gcn_W, ff_W1, ff_W2, wpack);
  k_init<<<kNT * kC / 256, 256, 0, stream>>>(depot_xy, customer_xy, demand,
                                             W_depot, b_depot, W_init, b_init, yB);
  for (int l = 0; l < kL; ++l) {
    const float* sp = (l == 0) ? nullptr : stats + ((l - 1) * 2 + 1) * 2 * kC;
    const float* gp = (l == 0) ? nullptr : bn_gamma + (l - 1) * kC;
    const float* bp = (l == 0) ? nullptr : bn_beta + (l - 1) * kC;
    float* s0 = stats + (l * 2 + 0) * 2 * kC;
    float* s1 = stats + (l * 2 + 1) * 2 * kC;
    const u16* wg  = wpack + (size_t)(l * 288 + 0) * 512;
    const u16* w1p = wpack + (size_t)(l * 288 + 32) * 512;
    const u16* w2p = wpack + (size_t)(l * 288 + 160) * 512;
    k_gemm<<<kNT / 32, 256, 0, stream>>>(yB, sp, gp, bp, wg, hbuf);
    k_agg<<<kB, 512, 0, stream>>>(yB, hbuf, sp, gp, bp, gcn_b + l * kC, s0, yA);
    k_ff<<<kNT / 32, 512, 0, stream>>>(yA, s0, bn_gamma + l * kC, bn_beta + l * kC,
                                       w1p, ff_b1 + l * kH,
                                       w2p, ff_b2 + l * kC,
                                       s1, yB);
  }
  k_out<<<kB, 512, 0, stream>>>(yB, stats + (2 * 2 + 1) * 2 * kC,
                                bn_gamma + 2 * kC, bn_beta + 2 * kC, (float*)d_out);
}

// Round 4
// 164.977 us; speedup vs baseline: 4.2782x; 1.1530x over previous
//
#include <hip/hip_runtime.h>

constexpr int kB = 256;
constexpr int kNC = 99;
constexpr int kN = 100;
constexpr int kC = 128;
constexpr int kH = 512;
constexpr int kL = 3;
constexpr int kNT = kB * kN;   // 25600
constexpr float kEps = 1e-5f;

typedef unsigned short u16;
typedef unsigned int u32;
typedef __attribute__((ext_vector_type(8))) __bf16 bf16x8;
typedef __attribute__((ext_vector_type(4))) float f32x4;

__device__ __forceinline__ u16 f2bf(float x) {
  union { float f; u32 u; } v; v.f = x;
  u32 r = (v.u + 0x7FFFu + ((v.u >> 16) & 1u)) >> 16;
  return (u16)r;
}

// per-channel BN affine from raw (sum, sumsq) stats; stats==nullptr -> identity
__device__ __forceinline__ void affine_from_stats(
    const float* __restrict__ stats, const float* __restrict__ gamma,
    const float* __restrict__ beta, int c, float& sc, float& sh) {
  if (stats != nullptr) {
    float s = stats[c], sq = stats[kC + c];
    float m = s * (1.0f / kNT);
    float v = sq * (1.0f / kNT) - m * m;
    float rs = rsqrtf(v + kEps);
    sc = gamma[c] * rs;
    sh = beta[c] - m * sc;
  } else {
    sc = 1.0f;
    sh = 0.0f;
  }
}

// ---- fused prep: weight pack (blocks 0..431) + initial embeddings (432..3631)
// pack layout: frag f; lane l; elem j: B[kb*32 + (l>>4)*8 + j][nb*16 + (l&15)]
//   gcn/W1: f = nb*4 + kb ; W2: f = nb*16 + kb
//   per layer: gcn frags [0,32), W1 [32,160), W2 [160,288), each frag 512 u16.
__global__ __launch_bounds__(256) void k_prep(
    const float* __restrict__ dxy, const float* __restrict__ cxy,
    const float* __restrict__ dem, const float* __restrict__ Wd,
    const float* __restrict__ bd, const float* __restrict__ Wi,
    const float* __restrict__ bi, const float* __restrict__ gcnW,
    const float* __restrict__ W1, const float* __restrict__ W2,
    float* __restrict__ yB, u16* __restrict__ wpack, float* __restrict__ stats) {
  if (blockIdx.x == 0) {
    for (int i = threadIdx.x; i < kL * 2 * 2 * kC; i += 256) stats[i] = 0.0f;
  }
  if (blockIdx.x < 432) {
    int g = blockIdx.x * 256 + threadIdx.x;          // < 110592 float4-groups
    int layer = g / 36864, r = g % 36864;
    const float* src; int shf; u16* base; int isW2 = 0;
    if (r < 4096) {
      src = gcnW + (size_t)layer * kC * kC; shf = 7;
      base = wpack + (size_t)(layer * 288 + 0) * 512;
    } else if (r < 20480) {
      src = W1 + (size_t)layer * kC * kH; shf = 9;
      base = wpack + (size_t)(layer * 288 + 32) * 512; r -= 4096;
    } else {
      src = W2 + (size_t)layer * kH * kC; shf = 7;
      base = wpack + (size_t)(layer * 288 + 160) * 512; r -= 20480; isW2 = 1;
    }
    int e4 = r * 4;
    int k = e4 >> shf, n0 = e4 & ((1 << shf) - 1);
    float4 v = *(const float4*)(src + ((size_t)k << shf) + n0);
    float vv[4] = {v.x, v.y, v.z, v.w};
    int kb = k >> 5, hi = (k >> 3) & 3, j = k & 7;
#pragma unroll
    for (int t = 0; t < 4; ++t) {
      int n = n0 + t;
      int nb = n >> 4, l = hi * 16 + (n & 15);
      int f = isW2 ? (nb * 16 + kb) : (nb * 4 + kb);
      base[(size_t)f * 512 + l * 8 + j] = f2bf(vv[t]);
    }
  } else {
    int g2 = (blockIdx.x - 432) * 256 + threadIdx.x;  // < 819200
    int row = g2 >> 5, c4 = (g2 & 31) * 4;
    int b = row / kN, j = row - b * kN;
    float4 o;
    if (j == 0) {
      float x0 = dxy[b * 2], x1 = dxy[b * 2 + 1];
      float4 w0 = *(const float4*)(Wd + c4);
      float4 w1 = *(const float4*)(Wd + kC + c4);
      float4 bb = *(const float4*)(bd + c4);
      o.x = fmaf(x0, w0.x, fmaf(x1, w1.x, bb.x));
      o.y = fmaf(x0, w0.y, fmaf(x1, w1.y, bb.y));
      o.z = fmaf(x0, w0.z, fmaf(x1, w1.z, bb.z));
      o.w = fmaf(x0, w0.w, fmaf(x1, w1.w, bb.w));
    } else {
      int q = b * kNC + (j - 1);
      float x0 = cxy[q * 2], x1 = cxy[q * 2 + 1], d = dem[q];
      float4 w0 = *(const float4*)(Wi + c4);
      float4 w1 = *(const float4*)(Wi + kC + c4);
      float4 w2 = *(const float4*)(Wi + 2 * kC + c4);
      float4 bb = *(const float4*)(bi + c4);
      o.x = fmaf(x0, w0.x, fmaf(x1, w1.x, fmaf(d, w2.x, bb.x)));
      o.y = fmaf(x0, w0.y, fmaf(x1, w1.y, fmaf(d, w2.y, bb.y)));
      o.z = fmaf(x0, w0.z, fmaf(x1, w1.z, fmaf(d, w2.z, bb.z)));
      o.w = fmaf(x0, w0.w, fmaf(x1, w1.w, fmaf(d, w2.w, bb.w)));
    }
    *(float4*)(yB + (size_t)row * kC + c4) = o;
  }
}

// ---- fused GCN layer: h = affine(yprev)@W (MFMA into LDS), then per-graph
// rsqrt-prefix + residual + gcn bias + BN stats. One block per graph, 8 waves.
__global__ __launch_bounds__(512) void k_gcn(
    const float* __restrict__ yprev, const float* __restrict__ stats_prev,
    const float* __restrict__ gamma_p, const float* __restrict__ beta_p,
    const u16* __restrict__ Wg, const float* __restrict__ gb,
    float* __restrict__ stats_out, float* __restrict__ yA) {
  __shared__ float s_scale[kC], s_shift[kC];
  __shared__ u16 xs[112][136];       // 30.5 KB, rows >=100 are dummy
  __shared__ float hs[kN][132];      // 52.8 KB (stride 132: conflict-light)
  __shared__ float sP[4][kC], s_sum[kC], s_sq[kC];
  const int tid = threadIdx.x;
  const int b = blockIdx.x;
  if (tid < kC) {
    affine_from_stats(stats_prev, gamma_p, beta_p, tid, s_scale[tid], s_shift[tid]);
    s_sum[tid] = 0.0f;
    s_sq[tid] = 0.0f;
  }
  __syncthreads();
  const size_t gbase = (size_t)b * kN * kC;
  // stage x (BN-affined, bf16) into LDS
#pragma unroll
  for (int i = 0; i < 7; ++i) {
    int li = i * 512 + tid;
    int lr = li >> 5, lc = (li & 31) * 4;
    float4 g = {0.f, 0.f, 0.f, 0.f};
    if (lr < kN) g = *(const float4*)(yprev + gbase + (size_t)lr * kC + lc);
    ushort4 h4;
    h4.x = f2bf(fmaf(g.x, s_scale[lc + 0], s_shift[lc + 0]));
    h4.y = f2bf(fmaf(g.y, s_scale[lc + 1], s_shift[lc + 1]));
    h4.z = f2bf(fmaf(g.z, s_scale[lc + 2], s_shift[lc + 2]));
    h4.w = f2bf(fmaf(g.w, s_scale[lc + 3], s_shift[lc + 3]));
    *(ushort4*)&xs[lr][lc] = h4;
  }
  __syncthreads();
  const int wave = tid >> 6, lane = tid & 63;
  const int arow = lane & 15, kofs = (lane >> 4) * 8;
  const int crow = (lane >> 4) * 4, ccol = lane & 15;
  // wave w owns output col block w*16; needs 4 B-frags, kept in regs
  bf16x8 bfr[4];
#pragma unroll
  for (int kb = 0; kb < 4; ++kb)
    bfr[kb] = *(const bf16x8*)(Wg + (size_t)(wave * 4 + kb) * 512 + lane * 8);
#pragma unroll
  for (int t = 0; t < 7; ++t) {
    f32x4 acc = {0.f, 0.f, 0.f, 0.f};
#pragma unroll
    for (int kb = 0; kb < 4; ++kb) {
      bf16x8 a = *(const bf16x8*)&xs[t * 16 + arow][kb * 32 + kofs];
      acc = __builtin_amdgcn_mfma_f32_16x16x32_bf16(a, bfr[kb], acc, 0, 0, 0);
    }
    int rbase = t * 16 + crow;
#pragma unroll
    for (int r = 0; r < 4; ++r)
      if (rbase + r < kN) hs[rbase + r][wave * 16 + ccol] = acc[r];
  }
  __syncthreads();
  // prefix over j (4-way split), residual, bias, stats
  const int c = tid & 127, jh = tid >> 7;
  const float sc = s_scale[c], sh = s_shift[c];
  const float gbc = gb[c];
  const int j0 = jh * 25;
  float p = 0.0f;
#pragma unroll
  for (int jj = 0; jj < 25; ++jj)
    p = fmaf(hs[j0 + jj][c], rsqrtf((float)(j0 + jj + 1)), p);
  sP[jh][c] = p;
  __syncthreads();
  float s = 0.0f;
  for (int q = 0; q < jh; ++q) s += sP[q][c];
  float lsum = 0.0f, lsq = 0.0f;
#pragma unroll
  for (int jj = 0; jj < 25; ++jj) {
    int j = j0 + jj;
    float r = rsqrtf((float)(j + 1));
    s = fmaf(hs[j][c], r, s);
    float xv = fmaf(yprev[gbase + (size_t)j * kC + c], sc, sh);
    float yv = xv + fmaf(s, r, gbc);
    yA[gbase + (size_t)j * kC + c] = yv;
    lsum += yv;
    lsq = fmaf(yv, yv, lsq);
  }
  atomicAdd(&s_sum[c], lsum);
  atomicAdd(&s_sq[c], lsq);
  __syncthreads();
  if (tid < kC) {
    atomicAdd(&stats_out[tid], s_sum[tid]);
    atomicAdd(&stats_out[kC + tid], s_sq[tid]);
  }
}

// fused FF (MFMA bf16): 32-row tile, 8 waves. phase1 N-split (64 cols/wave),
// phase2 N-split (16 cols/wave). hid transposed via LDS.
__global__ __launch_bounds__(512) void k_ff(
    const float* __restrict__ yA, const float* __restrict__ stats_in,
    const float* __restrict__ gamma, const float* __restrict__ beta,
    const u16* __restrict__ W1p, const float* __restrict__ b1,
    const u16* __restrict__ W2p, const float* __restrict__ b2,
    float* __restrict__ stats_out, float* __restrict__ yB) {
  __shared__ float s_scale[kC], s_shift[kC], s_sum[kC], s_sq[kC];
  __shared__ float s_b1[kH];
  __shared__ u16 xs[32][136];
  __shared__ u16 hid[32][520];
  const int tid = threadIdx.x;
  if (tid < kC) {
    affine_from_stats(stats_in, gamma, beta, tid, s_scale[tid], s_shift[tid]);
    s_sum[tid] = 0.0f;
    s_sq[tid] = 0.0f;
  }
  if (tid < 128) ((float4*)s_b1)[tid] = ((const float4*)b1)[tid];
  __syncthreads();
  const int rb = blockIdx.x * 32;
#pragma unroll
  for (int i = 0; i < 2; ++i) {
    int li = i * 2048 + tid * 4;
    int lr = li >> 7, lc = li & 127;
    float4 g = *(const float4*)(yA + (size_t)(rb + lr) * kC + lc);
    ushort4 h4;
    h4.x = f2bf(fmaf(g.x, s_scale[lc + 0], s_shift[lc + 0]));
    h4.y = f2bf(fmaf(g.y, s_scale[lc + 1], s_shift[lc + 1]));
    h4.z = f2bf(fmaf(g.z, s_scale[lc + 2], s_shift[lc + 2]));
    h4.w = f2bf(fmaf(g.w, s_scale[lc + 3], s_shift[lc + 3]));
    *(ushort4*)&xs[lr][lc] = h4;
  }
  __syncthreads();
  const int wave = tid >> 6, lane = tid & 63;
  const int arow = lane & 15, kofs = (lane >> 4) * 8;
  const int crow = (lane >> 4) * 4, ccol = lane & 15;
  bf16x8 a[2][4];
#pragma unroll
  for (int rb2 = 0; rb2 < 2; ++rb2)
#pragma unroll
    for (int kb = 0; kb < 4; ++kb)
      a[rb2][kb] = *(const bf16x8*)&xs[rb2 * 16 + arow][kb * 32 + kofs];

  // ---- phase 1: hid = relu(xs @ W1 + b1); wave handles nb = wave*4 .. wave*4+3
  const u16* w1f = W1p + lane * 8;
#pragma unroll
  for (int t = 0; t < 4; ++t) {
    const int nb = wave * 4 + t;
    f32x4 acc0 = {0.f, 0.f, 0.f, 0.f}, acc1 = {0.f, 0.f, 0.f, 0.f};
#pragma unroll
    for (int kb = 0; kb < 4; ++kb) {
      bf16x8 bfrag = *(const bf16x8*)(w1f + (size_t)(nb * 4 + kb) * 512);
      acc0 = __builtin_amdgcn_mfma_f32_16x16x32_bf16(a[0][kb], bfrag, acc0, 0, 0, 0);
      acc1 = __builtin_amdgcn_mfma_f32_16x16x32_bf16(a[1][kb], bfrag, acc1, 0, 0, 0);
    }
    const int c = nb * 16 + ccol;
    const float bbias = s_b1[c];
#pragma unroll
    for (int r = 0; r < 4; ++r) {
      hid[crow + r][c]      = f2bf(fmaxf(acc0[r] + bbias, 0.0f));
      hid[16 + crow + r][c] = f2bf(fmaxf(acc1[r] + bbias, 0.0f));
    }
  }
  __syncthreads();

  // ---- phase 2: out = x + hid @ W2 + b2; wave handles nb = wave
  const u16* w2f = W2p + lane * 8;
  f32x4 oacc0 = {0.f, 0.f, 0.f, 0.f}, oacc1 = {0.f, 0.f, 0.f, 0.f};
#pragma unroll
  for (int kb = 0; kb < 16; ++kb) {
    bf16x8 ha0 = *(const bf16x8*)&hid[arow][kb * 32 + kofs];
    bf16x8 ha1 = *(const bf16x8*)&hid[16 + arow][kb * 32 + kofs];
    bf16x8 bfrag = *(const bf16x8*)(w2f + (size_t)(wave * 16 + kb) * 512);
    oacc0 = __builtin_amdgcn_mfma_f32_16x16x32_bf16(ha0, bfrag, oacc0, 0, 0, 0);
    oacc1 = __builtin_amdgcn_mfma_f32_16x16x32_bf16(ha1, bfrag, oacc1, 0, 0, 0);
  }

  // ---- epilogue: bias + f32 residual, store, BN stats
  const int c = wave * 16 + ccol;
  const float sc = s_scale[c], sh = s_shift[c], bb = b2[c];
  float psum = 0.0f, psq = 0.0f;
#pragma unroll
  for (int rb2 = 0; rb2 < 2; ++rb2) {
#pragma unroll
    for (int r = 0; r < 4; ++r) {
      int row = rb + rb2 * 16 + crow + r;
      float xv = fmaf(yA[(size_t)row * kC + c], sc, sh);
      float o = (rb2 ? oacc1[r] : oacc0[r]) + bb + xv;
      yB[(size_t)row * kC + c] = o;
      psum += o;
      psq = fmaf(o, o, psq);
    }
  }
  atomicAdd(&s_sum[c], psum);
  atomicAdd(&s_sq[c], psq);
  __syncthreads();
  if (tid < kC) {
    atomicAdd(&stats_out[tid], s_sum[tid]);
    atomicAdd(&stats_out[kC + tid], s_sq[tid]);
  }
}

// final BN apply + nodes out + per-graph mean, 4-way j-split
__global__ __launch_bounds__(512) void k_out(
    const float* __restrict__ yB, const float* __restrict__ stats,
    const float* __restrict__ gamma, const float* __restrict__ beta,
    float* __restrict__ out) {
  __shared__ float sP[4][kC];
  const int b = blockIdx.x;
  const int c = threadIdx.x & 127, jh = threadIdx.x >> 7;
  float sc, sh;
  affine_from_stats(stats, gamma, beta, c, sc, sh);
  float acc = 0.0f;
  const size_t base = (size_t)b * kN * kC + c;
  const int j0 = jh * 25;
#pragma unroll
  for (int jj = 0; jj < 25; ++jj) {
    float xv = fmaf(yB[base + (size_t)(j0 + jj) * kC], sc, sh);
    out[base + (size_t)(j0 + jj) * kC] = xv;
    acc += xv;
  }
  sP[jh][c] = acc;
  __syncthreads();
  if (jh == 0)
    out[(size_t)kNT * kC + (size_t)b * kC + c] =
        (sP[0][c] + sP[1][c] + sP[2][c] + sP[3][c]) * (1.0f / kN);
}

extern "C" void kernel_launch(void* const* d_in, const int* in_sizes, int n_in,
                              void* d_out, int out_size, void* d_ws, size_t ws_size,
                              hipStream_t stream) {
  const float* depot_xy    = (const float*)d_in[0];
  const float* customer_xy = (const float*)d_in[1];
  const float* demand      = (const float*)d_in[2];
  const float* W_depot     = (const float*)d_in[3];
  const float* b_depot     = (const float*)d_in[4];
  const float* W_init      = (const float*)d_in[5];
  const float* b_init      = (const float*)d_in[6];
  const float* gcn_W       = (const float*)d_in[7];
  const float* gcn_b       = (const float*)d_in[8];
  const float* bn_gamma    = (const float*)d_in[9];
  const float* bn_beta     = (const float*)d_in[10];
  const float* ff_W1       = (const float*)d_in[11];
  const float* ff_b1       = (const float*)d_in[12];
  const float* ff_W2       = (const float*)d_in[13];
  const float* ff_b2       = (const float*)d_in[14];

  float* ws    = (float*)d_ws;
  float* yA    = ws;
  float* yB    = ws + (size_t)kNT * kC;
  float* stats = ws + 2 * (size_t)kNT * kC;   // 6 slots x (sum[128], sumsq[128])
  u16*   wpack = (u16*)(stats + kL * 2 * 2 * kC);

  k_prep<<<3632, 256, 0, stream>>>(depot_xy, customer_xy, demand, W_depot, b_depot,
                                   W_init, b_init, gcn_W, ff_W1, ff_W2,
                                   yB, wpack, stats);
  for (int l = 0; l < kL; ++l) {
    const float* sp = (l == 0) ? nullptr : stats + ((l - 1) * 2 + 1) * 2 * kC;
    const float* gp = (l == 0) ? nullptr : bn_gamma + (l - 1) * kC;
    const float* bp = (l == 0) ? nullptr : bn_beta + (l - 1) * kC;
    float* s0 = stats + (l * 2 + 0) * 2 * kC;
    float* s1 = stats + (l * 2 + 1) * 2 * kC;
    const u16* wg  = wpack + (size_t)(l * 288 + 0) * 512;
    const u16* w1p = wpack + (size_t)(l * 288 + 32) * 512;
    const u16* w2p = wpack + (size_t)(l * 288 + 160) * 512;
    k_gcn<<<kB, 512, 0, stream>>>(yB, sp, gp, bp, wg, gcn_b + l * kC, s0, yA);
    k_ff<<<kNT / 32, 512, 0, stream>>>(yA, s0, bn_gamma + l * kC, bn_beta + l * kC,
                                       w1p, ff_b1 + l * kH,
                                       w2p, ff_b2 + l * kC,
                                       s1, yB);
  }
  k_out<<<kB, 512, 0, stream>>>(yB, stats + (2 * 2 + 1) * 2 * kC,
                                bn_gamma + 2 * kC, bn_beta + 2 * kC, (float*)d_out);
}